// Round 9
// baseline (194.070 us; speedup 1.0000x reference)
//
#include <hip/hip_runtime.h>
#include <stdint.h>

// DenseCaps EM routing v7: B=32, I=2048, O=64, D=16, 3 EM iterations.
// lane <-> o. 1024 blocks (32 b x 32 chunks = 4/CU), 4 waves/block x 16 i.
// amdgpu_waves_per_eu(4,4) pins VGPR=128 spill-free (v4 lesson: compiler
// picks 64 + ~39MB/pass scratch spills). Manual 2-deep W-load pipeline.
// Expanded-quadratic logit (q=V^2 shared with S2). All-VALU DPP softmax,
// max-shift precomputed in fin_k. fin_k fuses chunk-reduce + finalize.
constexpr int Bn = 32, In = 2048;
constexpr float EPSF = 1e-7f;
constexpr int NC  = 32;        // i-chunks per batch
constexpr int IPB = In / NC;   // 64 i per block
constexpr int IPW = IPB / 4;   // 16 i per wave

template <int CTRL>
__device__ __forceinline__ float dpp_add(float x) {
  int y = __builtin_amdgcn_update_dpp(0, __float_as_int(x), CTRL, 0xF, 0xF, true);
  return x + __int_as_float(y);
}

__device__ __forceinline__ float wave_sum64(float x) {
  // rotate-reduce within 16-lane rows (all VALU, DPP), then cross-row swaps
  x = dpp_add<0x121>(x);  // row_ror:1
  x = dpp_add<0x122>(x);  // row_ror:2
  x = dpp_add<0x124>(x);  // row_ror:4
  x = dpp_add<0x128>(x);  // row_ror:8
#if __has_builtin(__builtin_amdgcn_permlane16_swap)
  {
    auto pr = __builtin_amdgcn_permlane16_swap(__float_as_uint(x), __float_as_uint(x), false, false);
    x = __uint_as_float(pr[0]) + __uint_as_float(pr[1]);
  }
#else
  x += __int_as_float(__builtin_amdgcn_ds_swizzle(__float_as_int(x), 0x401F));  // xor16
#endif
#if __has_builtin(__builtin_amdgcn_permlane32_swap)
  {
    auto pr = __builtin_amdgcn_permlane32_swap(__float_as_uint(x), __float_as_uint(x), false, false);
    x = __uint_as_float(pr[0]) + __uint_as_float(pr[1]);
  }
#else
  x += __shfl_xor(x, 32);
#endif
  return x;
}

// w[o][i][16] -> w_t[i][k][o] in float4 granularity (k = row of the 4x4)
__global__ __launch_bounds__(256) void transpose_w_k(const float4* __restrict__ w,
                                                     float4* __restrict__ w_t) {
  int idx = blockIdx.x * 256 + threadIdx.x;  // input float4 index: o*8192 + i*4 + k
  int o = idx >> 13;
  int rest = idx & 8191;
  int i = rest >> 2;
  int k = rest & 3;
  w_t[(size_t)((i << 2) + k) * 64 + o] = w[idx];
}

template <int TPASS>
__global__ __launch_bounds__(256)
__attribute__((amdgpu_waves_per_eu(4, 4)))  // pin 4 waves/EU -> 128 VGPR, no 64+spill
void pass_k(const float* __restrict__ poses,
            const float* __restrict__ a_in,
            const float* __restrict__ w_t,
            const float* __restrict__ params,
            float* __restrict__ partials) {
  const int gid = blockIdx.x;            // 1024 blocks
  const int xcd = gid & 7;
  const int s   = gid >> 3;              // 0..127
  const int b   = s & 31;                // batch fastest within an XCD slice
  const int cc  = xcd * 4 + (s >> 5);    // chunk 0..31; each XCD owns 4 chunks of w_t
  const int tid = threadIdx.x, wv = tid >> 6, ln = tid & 63;
  const int i0 = __builtin_amdgcn_readfirstlane(cc * IPB + wv * IPW);  // wave-uniform

  // per-lane (=per-o) constants, expanded-quadratic form:
  // u = k0 + sum_d (k1[d]*V[d] - k2[d]*V[d]^2)
  float k0 = 0.f, k1[16], k2[16];
  if (TPASS > 0) {
    const float4* pp4 = (const float4*)(params + (size_t)(b * 64 + ln) * 36);
    float mu[16];
#pragma unroll
    for (int k = 0; k < 4; ++k) {
      float4 v = pp4[k];
      mu[4 * k] = v.x; mu[4 * k + 1] = v.y; mu[4 * k + 2] = v.z; mu[4 * k + 3] = v.w;
    }
#pragma unroll
    for (int k = 0; k < 4; ++k) {
      float4 v = pp4[4 + k];
      k2[4 * k] = v.x; k2[4 * k + 1] = v.y; k2[4 * k + 2] = v.z; k2[4 * k + 3] = v.w;
    }
    k0 = ((const float*)pp4)[32];  // log(a_out+eps)-0.5*sum log sig2 - max_o
#pragma unroll
    for (int d = 0; d < 16; ++d) {
      k1[d] = 2.f * k2[d] * mu[d];
      k0 = fmaf(-k2[d], mu[d] * mu[d], k0);
    }
  }

  float rs = 0.f, S1[16], S2[16];
#pragma unroll
  for (int d = 0; d < 16; ++d) { S1[d] = 0.f; S2[d] = 0.f; }

  const float4* wt4 = (const float4*)w_t;
  const float* pbase = poses + ((size_t)b * In + i0) * 16;  // wave-uniform -> s_load
  const float* abase = a_in + (size_t)b * In + i0;

  // 2-deep software pipeline on the W loads
  float4 cw0 = wt4[(size_t)(i0 * 4 + 0) * 64 + ln];
  float4 cw1 = wt4[(size_t)(i0 * 4 + 1) * 64 + ln];
  float4 cw2 = wt4[(size_t)(i0 * 4 + 2) * 64 + ln];
  float4 cw3 = wt4[(size_t)(i0 * 4 + 3) * 64 + ln];

#pragma unroll 4
  for (int ii = 0; ii < IPW; ++ii) {
    const int inx = (ii + 1 < IPW) ? (i0 + ii + 1) : (i0 + ii);
    float4 nw0 = wt4[(size_t)(inx * 4 + 0) * 64 + ln];
    float4 nw1 = wt4[(size_t)(inx * 4 + 1) * 64 + ln];
    float4 nw2 = wt4[(size_t)(inx * 4 + 2) * 64 + ln];
    float4 nw3 = wt4[(size_t)(inx * 4 + 3) * 64 + ln];

    const float4* pp = (const float4*)(pbase + ii * 16);
    float4 p0 = pp[0], p1 = pp[1], p2 = pp[2], p3 = pp[3];  // uniform scalars
    float V[16], q[16];
#define VROW(p, Pv)                                                                    \
    V[p * 4 + 0] = fmaf(Pv.w, cw3.x, fmaf(Pv.z, cw2.x, fmaf(Pv.y, cw1.x, Pv.x * cw0.x))); \
    V[p * 4 + 1] = fmaf(Pv.w, cw3.y, fmaf(Pv.z, cw2.y, fmaf(Pv.y, cw1.y, Pv.x * cw0.y))); \
    V[p * 4 + 2] = fmaf(Pv.w, cw3.z, fmaf(Pv.z, cw2.z, fmaf(Pv.y, cw1.z, Pv.x * cw0.z))); \
    V[p * 4 + 3] = fmaf(Pv.w, cw3.w, fmaf(Pv.z, cw2.w, fmaf(Pv.y, cw1.w, Pv.x * cw0.w)));
    VROW(0, p0) VROW(1, p1) VROW(2, p2) VROW(3, p3)
#undef VROW
#pragma unroll
    for (int d = 0; d < 16; ++d) q[d] = V[d] * V[d];

    const float a = abase[ii];
    float r;
    if (TPASS == 0) {
      r = a * 0.015625f;  // R uniform at t=0
    } else {
      float u0 = k0, u1 = 0.f, u2 = 0.f, u3 = 0.f;
#pragma unroll
      for (int j = 0; j < 4; ++j) {
        u0 = fmaf(-k2[j], q[j], fmaf(k1[j], V[j], u0));
        u1 = fmaf(-k2[4 + j], q[4 + j], fmaf(k1[4 + j], V[4 + j], u1));
        u2 = fmaf(-k2[8 + j], q[8 + j], fmaf(k1[8 + j], V[8 + j], u2));
        u3 = fmaf(-k2[12 + j], q[12 + j], fmaf(k1[12 + j], V[12 + j], u3));
      }
      float u = (u0 + u1) + (u2 + u3);
      float e = __expf(u);                 // u <= 0 by construction (max-shift)
      float ss = wave_sum64(e) + 1e-37f;
      r = a * e * __builtin_amdgcn_rcpf(ss);
    }
    rs += r;
#pragma unroll
    for (int d = 0; d < 16; ++d) {
      S1[d] = fmaf(r, V[d], S1[d]);
      S2[d] = fmaf(r, q[d], S2[d]);
    }
    cw0 = nw0; cw1 = nw1; cw2 = nw2; cw3 = nw3;
  }

  // 4-wave LDS reduce -> one partial row per (b, cc)
  __shared__ float lds[4][33][64];
  lds[wv][0][ln] = rs;
#pragma unroll
  for (int d = 0; d < 16; ++d) {
    lds[wv][1 + d][ln] = S1[d];
    lds[wv][17 + d][ln] = S2[d];
  }
  __syncthreads();
  for (int idx = tid; idx < 33 * 64; idx += 256) {
    int j = idx >> 6, o = idx & 63;
    float ssum = lds[0][j][o] + lds[1][j][o] + lds[2][j][o] + lds[3][j][o];
    partials[((size_t)(b * NC + cc) * 33 + j) * 64 + o] = ssum;
  }
}

// fused chunk-reduce + finalize: one block per b
template <int TPASS>
__global__ __launch_bounds__(256) void fin_k(const float* __restrict__ partials,
                                             const float* __restrict__ beta_a,
                                             const float* __restrict__ beta_u,
                                             float* __restrict__ params,
                                             float* __restrict__ out) {
  const int b = blockIdx.x;
  const int tid = threadIdx.x;
  __shared__ float redL[33 * 64];
  for (int idx = tid; idx < 33 * 64; idx += 256) {  // coalesced across tid
    const float* base = partials + (size_t)b * NC * 2112 + idx;
    float s = 0.f;
#pragma unroll 8
    for (int c = 0; c < NC; ++c) s += base[(size_t)c * 2112];
    redL[idx] = s;
  }
  __syncthreads();
  if (tid < 64) {
    const int o = tid;
    const float r_sum = redL[o] + EPSF;
    const float inv = 1.f / r_sum;
    float muv[16], sg[16], lsum = 0.f;
#pragma unroll
    for (int d = 0; d < 16; ++d) {
      float m = redL[(1 + d) * 64 + o] * inv;
      float s2 = fmaxf(redL[(17 + d) * 64 + o] * inv - m * m, 0.f) + EPSF;  // E[V^2]-mu^2
      muv[d] = m; sg[d] = s2; lsum += logf(s2);
    }
    const float cost = (16.f * beta_u[o] + 0.5f * lsum) * r_sum;
    const float aout = 1.f / (1.f + __expf(-(float)(TPASS + 1) * (beta_a[o] - cost)));
    if (TPASS < 2) {
      float c0 = logf(aout + EPSF) - 0.5f * lsum;
      float mx = c0;  // wave-wide max over o
#pragma unroll
      for (int k = 1; k < 64; k <<= 1) mx = fmaxf(mx, __shfl_xor(mx, k));
      float* pp = params + (size_t)(b * 64 + o) * 36;
#pragma unroll
      for (int d = 0; d < 16; ++d) {
        pp[d] = muv[d];
        pp[16 + d] = 0.5f / sg[d];
      }
      pp[32] = c0 - mx;  // pre-shifted logit constant
    } else {
      const int g = b * 64 + o;
#pragma unroll
      for (int d = 0; d < 16; ++d) out[(size_t)g * 16 + d] = muv[d];
      out[Bn * 64 * 16 + g] = aout;
    }
  }
}

extern "C" void kernel_launch(void* const* d_in, const int* in_sizes, int n_in,
                              void* d_out, int out_size, void* d_ws, size_t ws_size,
                              hipStream_t stream) {
  const float* poses  = (const float*)d_in[0];
  const float* a_in   = (const float*)d_in[1];
  const float* w      = (const float*)d_in[2];
  const float* beta_a = (const float*)d_in[3];
  const float* beta_u = (const float*)d_in[4];
  float* out = (float*)d_out;

  float* w_t      = (float*)d_ws;                          // 8 MB
  float* partials = w_t + (size_t)In * 64 * 16;            // 8.65 MB
  float* params   = partials + (size_t)Bn * NC * 33 * 64;  // 295 KB

  transpose_w_k<<<dim3(In * 64 * 4 / 256), 256, 0, stream>>>((const float4*)w, (float4*)w_t);

  dim3 pg(Bn * NC);  // 1024 blocks = exactly 4/CU (128 VGPR, 33KB LDS)
  pass_k<0><<<pg, 256, 0, stream>>>(poses, a_in, w_t, params, partials);
  fin_k<0><<<Bn, 256, 0, stream>>>(partials, beta_a, beta_u, params, out);
  pass_k<1><<<pg, 256, 0, stream>>>(poses, a_in, w_t, params, partials);
  fin_k<1><<<Bn, 256, 0, stream>>>(partials, beta_a, beta_u, params, out);
  pass_k<2><<<pg, 256, 0, stream>>>(poses, a_in, w_t, params, partials);
  fin_k<2><<<Bn, 256, 0, stream>>>(partials, beta_a, beta_u, params, out);
}